// Round 2
// baseline (306.161 us; speedup 1.0000x reference)
//
#include <hip/hip_runtime.h>

// MultiRegionalFusionModule: out[b,t,s,f] = tgt[b,t,s,f] +
//   sum_k softmax_k(corr[tci[b,t], ri[k]]) * rv[b,k,f,s]
// B=8 T=32 S=512 F=128 K=64 N=200, fp32 (indices int32 from harness).
//
// R4 == R3 resubmit (R3 bench died to container-acquisition infra failure,
// no kernel signal). Theory unchanged:
// R2 was latency-bound (HBM 22%, VALU 19%, Occ 35%, VGPR=52 < 64 acc
// floats => compiler serialized loads to ~1-2 outstanding/wave).
// Changes vs R2: dwordx4 rv loads (16B/lane), acc halved to 32 VGPR
// (F_TILE 16->8), grid 2048 with LDS 15.4KB and __launch_bounds__(256,8)
// -> 32 waves/CU (whole grid co-resident). fb in HIGH bits of blockIdx so
// XCD = bid%8 depends only on (b,sb): all 16 fb-siblings of an out-row
// share one XCD's L2 -> full 128B-line writebacks despite 32B per-block
// store segments.

constexpr int Bn = 8, Tn = 32, Sn = 512, Fn = 128, Kn = 64, Nn = 200;
constexpr int S_TILE = 32;
constexpr int F_TILE = 8;
// grid = (Fn/F_TILE) * Bn * (Sn/S_TILE) = 16 * 8 * 16 = 2048 blocks of 256

#define FMA4(A, V, S)                                        \
    (A).x = fmaf((V).x, (S), (A).x);                         \
    (A).y = fmaf((V).y, (S), (A).y);                         \
    (A).z = fmaf((V).z, (S), (A).z);                         \
    (A).w = fmaf((V).w, (S), (A).w)

__global__ __launch_bounds__(256, 8)
void mrf_kernel(const float* __restrict__ tgt,
                const float* __restrict__ rv,
                const float* __restrict__ corr,
                const int*   __restrict__ tci,
                const int*   __restrict__ ri,
                float*       __restrict__ out)
{
    // attnT rows padded to 36 floats (144B): float4 reads stay 16B-aligned,
    // main-loop reads are same-address broadcasts (conflict-free).
    __shared__ float attnT[Kn][36];
    // per-WAVE epilogue transpose tile: no __syncthreads needed (same-wave
    // DS ops execute in issue order). Row pad 8->12 keeps float4 reads
    // 16B-aligned (48B row stride); worst-case 4-way bank aliasing,
    // epilogue-only.
    __shared__ float etile[4][S_TILE][12];

    const int tid  = threadIdx.x;
    const int w    = tid >> 6;    // wave -> t chunk of 8
    const int lane = tid & 63;

    const int bid = blockIdx.x;
    const int fb  = bid >> 7;         // slowest: fb-siblings same XCD (bid%8)
    const int r_  = bid & 127;
    const int b   = r_ >> 4;
    const int sb  = r_ & 15;
    const int s0  = sb * S_TILE;
    const int f0  = fb * F_TILE;

    // ---- prologue: softmax over K (lane = k) for this b's 32 t rows ----
    {
        const int rik = ri[lane];
        #pragma unroll
        for (int j = 0; j < 8; ++j) {
            const int t   = w + 4 * j;
            const int row = tci[b * Tn + t];
            float c = corr[row * Nn + rik];
            float m = c;
            #pragma unroll
            for (int off = 32; off; off >>= 1)
                m = fmaxf(m, __shfl_xor(m, off));
            float e = __expf(c - m);
            float s = e;
            #pragma unroll
            for (int off = 32; off; off >>= 1)
                s += __shfl_xor(s, off);
            attnT[lane][t] = e / s;
        }
    }
    __syncthreads();

    // ---- main loop over k ----
    // lane covers: s = s0 + 4*sq + [0..3] (float4 along s), f = f0 + fr
    const int t0 = w * 8;
    const int sq = lane & 7;      // s quad index (8 quads x 4 = 32 s)
    const int fr = lane >> 3;     // f row 0..7 (8 x 128B segments per load)

    float4 acc[8];                // [t] ; 32 VGPRs
    #pragma unroll
    for (int tt = 0; tt < 8; ++tt) {
        acc[tt].x = 0.0f; acc[tt].y = 0.0f;
        acc[tt].z = 0.0f; acc[tt].w = 0.0f;
    }

    // rv index: ((b*K + k)*F + f)*S + s
    const float* rvp = rv + ((size_t)(b * Kn) * Fn + f0 + fr) * (size_t)Sn
                          + s0 + 4 * sq;

    #pragma unroll 2
    for (int k = 0; k < Kn; ++k) {
        const float4 v4 = *(const float4*)(rvp + (size_t)k * (Fn * Sn));
        const float4 a0 = *(const float4*)&attnT[k][t0];       // broadcast
        const float4 a1 = *(const float4*)&attnT[k][t0 + 4];   // broadcast
        FMA4(acc[0], v4, a0.x);
        FMA4(acc[1], v4, a0.y);
        FMA4(acc[2], v4, a0.z);
        FMA4(acc[3], v4, a0.w);
        FMA4(acc[4], v4, a1.x);
        FMA4(acc[5], v4, a1.y);
        FMA4(acc[6], v4, a1.z);
        FMA4(acc[7], v4, a1.w);
    }

    // ---- epilogue: per-wave LDS transpose (s-fast regs -> f-fast stores)
    //      + residual add, all float4 ----
    const int ss = lane >> 1;     // s row for read-back/stores (0..31)
    const int fh = lane & 1;      // f half: float4 at f0 + 4*fh
    float* et = &etile[w][0][0];

    #pragma unroll
    for (int tt = 0; tt < 8; ++tt) {
        // scatter this t's column into the wave tile
        et[(4 * sq + 0) * 12 + fr] = acc[tt].x;
        et[(4 * sq + 1) * 12 + fr] = acc[tt].y;
        et[(4 * sq + 2) * 12 + fr] = acc[tt].z;
        et[(4 * sq + 3) * 12 + fr] = acc[tt].w;
        // same-wave DS ordering guarantees write->read visibility
        const int t = t0 + tt;
        const size_t rb = (((size_t)(b * Tn + t)) * Sn + s0 + ss) * (size_t)Fn
                          + f0 + 4 * fh;
        const float4 tv = *(const float4*)(tgt + rb);
        const float4 cv = *(const float4*)&et[ss * 12 + 4 * fh];
        float4 o;
        o.x = tv.x + cv.x; o.y = tv.y + cv.y;
        o.z = tv.z + cv.z; o.w = tv.w + cv.w;
        *(float4*)(out + rb) = o;
    }
}

extern "C" void kernel_launch(void* const* d_in, const int* in_sizes, int n_in,
                              void* d_out, int out_size, void* d_ws, size_t ws_size,
                              hipStream_t stream)
{
    const float* tgt  = (const float*)d_in[0];   // [B,T,S,F]
    const float* rv   = (const float*)d_in[1];   // [B,K,F,S]
    const float* corr = (const float*)d_in[2];   // [N,N]
    const int*   tci  = (const int*)d_in[3];     // [B,T]
    const int*   ri   = (const int*)d_in[4];     // [K]
    float*       out  = (float*)d_out;           // [B,T,S,F]

    dim3 grid((Fn / F_TILE) * Bn * (Sn / S_TILE));  // 2048
    dim3 block(256);
    hipLaunchKernelGGL(mrf_kernel, grid, block, 0, stream,
                       tgt, rv, corr, tci, ri, out);
}

// Round 3
// 279.042 us; speedup vs baseline: 1.0972x; 1.0972x over previous
//
#include <hip/hip_runtime.h>

// MultiRegionalFusionModule: out[b,t,s,f] = tgt[b,t,s,f] +
//   sum_k softmax_k(corr[tci[b,t], ri[k]]) * rv[b,k,f,s]
// B=8 T=32 S=512 F=128 K=64 N=200, fp32.
//
// R5: R2/R4 showed BW invariant at 1.75 TB/s (22%) across 2x occupancy ->
// pattern-limited, not latency-limited. Root cause: 128B read granule at
// 2KB stride (block footprint S_TILE*4B per f-row). Reads want s-contig,
// writes want f-contig; register budget forbids both in one kernel.
// Split: phase A writes ctx[b,t,f,s] with 1KB-contiguous reads AND writes;
// phase B is a 64x64 LDS transpose-add (256B granules, 64B store segs).

constexpr int Bn = 8, Tn = 32, Sn = 512, Fn = 128, Kn = 64, Nn = 200;

#define FMA4(A, V, S)                                        \
    (A).x = fmaf((V).x, (S), (A).x);                         \
    (A).y = fmaf((V).y, (S), (A).y);                         \
    (A).z = fmaf((V).z, (S), (A).z);                         \
    (A).w = fmaf((V).w, (S), (A).w)

// ---------- Phase A: ctx[b,t,f,s] = sum_k attn[b,t,k] * rv[b,k,f,s] -------
// grid 512 = b(8) x fp(64); block 1024 = 16 waves.
// wave w: sh=w&1 (s half), fi=(w>>1)&1 (f within pair), tg=w>>2 (t chunk of 8)
// lane: s = sh*256 + lane*4  -> one global_load_dwordx4 per k = 1KB contig.
__global__ __launch_bounds__(1024, 8)
void mrf_ctx(const float* __restrict__ rv,
             const float* __restrict__ corr,
             const int*   __restrict__ tci,
             const int*   __restrict__ ri,
             float*       __restrict__ ctx)
{
    __shared__ float attnT[Kn][36];   // rows 144B: float4 reads 16B-aligned

    const int tid  = threadIdx.x;
    const int w    = tid >> 6;
    const int lane = tid & 63;
    const int bid  = blockIdx.x;
    const int b    = bid >> 6;
    const int fp   = bid & 63;

    // softmax over K (lane = k); 16 waves x 2 rounds cover t = 0..31
    {
        const int rik = ri[lane];
        #pragma unroll
        for (int j = 0; j < 2; ++j) {
            const int t   = w + 16 * j;
            const int row = tci[b * Tn + t];
            float c = corr[row * Nn + rik];
            float m = c;
            #pragma unroll
            for (int off = 32; off; off >>= 1)
                m = fmaxf(m, __shfl_xor(m, off));
            float e = __expf(c - m);
            float s = e;
            #pragma unroll
            for (int off = 32; off; off >>= 1)
                s += __shfl_xor(s, off);
            attnT[lane][t] = e / s;
        }
    }
    __syncthreads();

    const int sh = w & 1;
    const int fi = (w >> 1) & 1;
    const int tg = w >> 2;
    const int t0 = tg * 8;
    const int f  = fp * 2 + fi;

    const float* rvp = rv + ((size_t)(b * Kn) * Fn + f) * (size_t)Sn
                          + sh * 256 + lane * 4;

    float4 c0 = make_float4(0.f, 0.f, 0.f, 0.f), c1 = c0, c2 = c0, c3 = c0,
           c4 = c0, c5 = c0, c6 = c0, c7 = c0;

    #pragma unroll 2
    for (int k = 0; k < Kn; ++k) {
        const float4 v  = *(const float4*)(rvp + (size_t)k * (Fn * Sn));
        const float4 a0 = *(const float4*)&attnT[k][t0];       // broadcast
        const float4 a1 = *(const float4*)&attnT[k][t0 + 4];   // broadcast
        FMA4(c0, v, a0.x); FMA4(c1, v, a0.y);
        FMA4(c2, v, a0.z); FMA4(c3, v, a0.w);
        FMA4(c4, v, a1.x); FMA4(c5, v, a1.y);
        FMA4(c6, v, a1.z); FMA4(c7, v, a1.w);
    }

    // ctx stores: 1KB contiguous per (t, f-row) per wave
    float* cp = ctx + ((size_t)(b * Tn + t0) * Fn + f) * (size_t)Sn
                    + sh * 256 + lane * 4;
    const size_t ts = (size_t)Fn * Sn;   // t stride in floats
    *(float4*)(cp + 0 * ts) = c0;
    *(float4*)(cp + 1 * ts) = c1;
    *(float4*)(cp + 2 * ts) = c2;
    *(float4*)(cp + 3 * ts) = c3;
    *(float4*)(cp + 4 * ts) = c4;
    *(float4*)(cp + 5 * ts) = c5;
    *(float4*)(cp + 6 * ts) = c6;
    *(float4*)(cp + 7 * ts) = c7;
}

// ---------- Phase B: out[b,t,s,f] = tgt[b,t,s,f] + ctx[b,t,f,s] -----------
// grid 4096 = b(8) x t(32) x sg(8) x fg(2); block 256. 64x64 LDS transpose.
// pad 65: both LDS phases measured-pattern <=2-way bank alias (free).
__global__ __launch_bounds__(256, 8)
void mrf_tadd(const float* __restrict__ tgt,
              const float* __restrict__ ctx,
              float*       __restrict__ out)
{
    __shared__ float tile[64][65];

    const int tid = threadIdx.x;
    const int bid = blockIdx.x;
    const int fg  = bid & 1;
    const int sg  = (bid >> 1) & 7;
    const int t   = (bid >> 4) & 31;
    const int b   = bid >> 9;
    const int s0  = sg * 64;
    const int f0  = fg * 64;

    const int r0 = tid >> 4;          // 0..15
    const int x4 = (tid & 15) * 4;    // 0,4,..,60

    // read ctx[f-local][s-local]: 16 lanes x 16B = 256B per f-row
    const size_t cbase = ((size_t)(b * Tn + t) * Fn + f0) * (size_t)Sn + s0;
    #pragma unroll
    for (int p = 0; p < 4; ++p) {
        const int r = p * 16 + r0;
        const float4 v = *(const float4*)(ctx + cbase + (size_t)r * Sn + x4);
        tile[r][x4 + 0] = v.x;
        tile[r][x4 + 1] = v.y;
        tile[r][x4 + 2] = v.z;
        tile[r][x4 + 3] = v.w;
    }
    __syncthreads();

    // write out[s-local][f-local] + tgt: 64B segments per s-row (R2-clean)
    const size_t obase = ((size_t)(b * Tn + t) * Sn + s0) * (size_t)Fn + f0;
    #pragma unroll
    for (int p = 0; p < 4; ++p) {
        const int ss = p * 16 + r0;
        const size_t o = obase + (size_t)ss * Fn + x4;
        const float4 tv = *(const float4*)(tgt + o);
        float4 ov;
        ov.x = tv.x + tile[x4 + 0][ss];
        ov.y = tv.y + tile[x4 + 1][ss];
        ov.z = tv.z + tile[x4 + 2][ss];
        ov.w = tv.w + tile[x4 + 3][ss];
        *(float4*)(out + o) = ov;
    }
}

// ---------- Fallback (R4 single-kernel, harness-verified) ------------------
constexpr int S_TILE = 32;
constexpr int F_TILE = 8;

__global__ __launch_bounds__(256, 8)
void mrf_fallback(const float* __restrict__ tgt,
                  const float* __restrict__ rv,
                  const float* __restrict__ corr,
                  const int*   __restrict__ tci,
                  const int*   __restrict__ ri,
                  float*       __restrict__ out)
{
    __shared__ float attnT[Kn][36];
    __shared__ float etile[4][S_TILE][12];

    const int tid  = threadIdx.x;
    const int w    = tid >> 6;
    const int lane = tid & 63;

    const int bid = blockIdx.x;
    const int fb  = bid >> 7;
    const int r_  = bid & 127;
    const int b   = r_ >> 4;
    const int sb  = r_ & 15;
    const int s0  = sb * S_TILE;
    const int f0  = fb * F_TILE;

    {
        const int rik = ri[lane];
        #pragma unroll
        for (int j = 0; j < 8; ++j) {
            const int t   = w + 4 * j;
            const int row = tci[b * Tn + t];
            float c = corr[row * Nn + rik];
            float m = c;
            #pragma unroll
            for (int off = 32; off; off >>= 1)
                m = fmaxf(m, __shfl_xor(m, off));
            float e = __expf(c - m);
            float s = e;
            #pragma unroll
            for (int off = 32; off; off >>= 1)
                s += __shfl_xor(s, off);
            attnT[lane][t] = e / s;
        }
    }
    __syncthreads();

    const int t0 = w * 8;
    const int sq = lane & 7;
    const int fr = lane >> 3;

    float4 acc[8];
    #pragma unroll
    for (int tt = 0; tt < 8; ++tt) {
        acc[tt].x = 0.0f; acc[tt].y = 0.0f;
        acc[tt].z = 0.0f; acc[tt].w = 0.0f;
    }

    const float* rvp = rv + ((size_t)(b * Kn) * Fn + f0 + fr) * (size_t)Sn
                          + s0 + 4 * sq;

    #pragma unroll 2
    for (int k = 0; k < Kn; ++k) {
        const float4 v4 = *(const float4*)(rvp + (size_t)k * (Fn * Sn));
        const float4 a0 = *(const float4*)&attnT[k][t0];
        const float4 a1 = *(const float4*)&attnT[k][t0 + 4];
        FMA4(acc[0], v4, a0.x); FMA4(acc[1], v4, a0.y);
        FMA4(acc[2], v4, a0.z); FMA4(acc[3], v4, a0.w);
        FMA4(acc[4], v4, a1.x); FMA4(acc[5], v4, a1.y);
        FMA4(acc[6], v4, a1.z); FMA4(acc[7], v4, a1.w);
    }

    const int ss = lane >> 1;
    const int fh = lane & 1;
    float* et = &etile[w][0][0];

    #pragma unroll
    for (int tt = 0; tt < 8; ++tt) {
        et[(4 * sq + 0) * 12 + fr] = acc[tt].x;
        et[(4 * sq + 1) * 12 + fr] = acc[tt].y;
        et[(4 * sq + 2) * 12 + fr] = acc[tt].z;
        et[(4 * sq + 3) * 12 + fr] = acc[tt].w;
        const int t = t0 + tt;
        const size_t rb = (((size_t)(b * Tn + t)) * Sn + s0 + ss) * (size_t)Fn
                          + f0 + 4 * fh;
        const float4 tv = *(const float4*)(tgt + rb);
        const float4 cv = *(const float4*)&et[ss * 12 + 4 * fh];
        float4 o;
        o.x = tv.x + cv.x; o.y = tv.y + cv.y;
        o.z = tv.z + cv.z; o.w = tv.w + cv.w;
        *(float4*)(out + rb) = o;
    }
}

extern "C" void kernel_launch(void* const* d_in, const int* in_sizes, int n_in,
                              void* d_out, int out_size, void* d_ws, size_t ws_size,
                              hipStream_t stream)
{
    const float* tgt  = (const float*)d_in[0];   // [B,T,S,F]
    const float* rv   = (const float*)d_in[1];   // [B,K,F,S]
    const float* corr = (const float*)d_in[2];   // [N,N]
    const int*   tci  = (const int*)d_in[3];     // [B,T]
    const int*   ri   = (const int*)d_in[4];     // [K]
    float*       out  = (float*)d_out;           // [B,T,S,F]

    const size_t ctx_bytes = (size_t)Bn * Tn * Fn * Sn * sizeof(float); // 64 MiB
    if (ws_size >= ctx_bytes) {
        float* ctx = (float*)d_ws;               // [B,T,F,S]
        hipLaunchKernelGGL(mrf_ctx, dim3(Bn * (Fn / 2)), dim3(1024), 0, stream,
                           rv, corr, tci, ri, ctx);
        hipLaunchKernelGGL(mrf_tadd, dim3(Bn * Tn * (Sn / 64) * (Fn / 64)),
                           dim3(256), 0, stream, tgt, ctx, out);
    } else {
        hipLaunchKernelGGL(mrf_fallback, dim3(2048), dim3(256), 0, stream,
                           tgt, rv, corr, tci, ri, out);
    }
}